// Round 9
// baseline (70.097 us; speedup 1.0000x reference)
//
#include <hip/hip_runtime.h>

#define NJ   16
#define DM   128
#define NH   8
#define P    8          // positions per block (4 waves x 2 positions)
#define CL   0.36067376022224085f   // 0.25 * log2(e): folds score scale + exp->exp2

typedef __attribute__((ext_vector_type(8))) short bf16x8;
typedef __attribute__((ext_vector_type(4))) float f32x4;

// Kinematic adjacency (compile-time constant of the reference), UNscaled.
__constant__ float c_adj[NJ * NJ] = {
    1,1,0,0, 1,0,0,1, 0,0,1,0, 0,1,0,0,
    1,1,1,0, 0,0,0,0, 0,0,0,0, 0,0,0,0,
    0,1,1,1, 0,0,0,0, 0,0,0,0, 0,0,0,0,
    0,0,1,1, 0,0,0,0, 0,0,0,0, 0,0,0,0,
    1,0,0,0, 1,1,0,0.8f, 0,0,0,0, 0,0,0,0,
    0,0,0,0, 1,1,1,0, 0.8f,0,0,0, 0,0,0,0,
    0,0,0,0, 0,1,1,0, 0,0.8f,0,0, 0,0,0,0,
    1,0,0,0, 0.8f,0,0,1, 1,0,0,0, 0,0,0,0,
    0,0,0,0, 0,0.8f,0,1, 1,1,0,0, 0,0,0,0,
    0,0,0,0, 0,0,0.8f,0, 1,1,0,0, 0,0,0,0,
    1,0,0,0, 0,0,0,0, 0,0,1,1, 0,0.8f,0,0,
    0,0,0,0, 0,0,0,0, 0,0,1,1, 1,0,0.8f,0,
    0,0,0,0, 0,0,0,0, 0,0,0,1, 1,0,0,0.8f,
    1,0,0,0, 0,0,0,0, 0,0,0.8f,0, 0,1,1,0,
    0,0,0,0, 0,0,0,0, 0,0,0,0.8f, 0,1,1,1,
    0,0,0,0, 0,0,0,0, 0,0,0,0, 0.8f,0,1,1
};

// ws layout (32-bit words):
//   [0,128)     bp[128] fp32        : bv @ Wo + bo
//   [128,256)   pack[8][16] fp32    : per head: M*CL(9), a*CL(3), c*CL(3), d*CL(1)
//   [256,2304)  Gfrag[8][64][4] u32 : bf16x2-packed fragments, k = 4h+r (r==3 -> 0)
#define WS_BP_W   0
#define WS_PACK_W 128
#define WS_GF_W   256

__device__ __forceinline__ unsigned short f2bf(float f) {
    union { float f; unsigned u; } v; v.f = f;
    unsigned u = v.u;
    u += 0x7FFFu + ((u >> 16) & 1u);          // RNE
    return (unsigned short)(u >> 16);
}
__device__ __forceinline__ unsigned pack2bf(float lo, float hi) {
    return (unsigned)f2bf(lo) | ((unsigned)f2bf(hi) << 16);
}

__global__ __launch_bounds__(256) void skel_setup_kernel(
    const float* __restrict__ Wq, const float* __restrict__ bq,
    const float* __restrict__ Wk, const float* __restrict__ bk,
    const float* __restrict__ Wv, const float* __restrict__ bv,
    const float* __restrict__ Wo, const float* __restrict__ bo,
    unsigned* __restrict__ wsu)
{
    const int b = blockIdx.x, t = threadIdx.x;
    float* wsf = (float*)wsu;

    if (b < 8) {
        // One packed u32 (2 bf16, k-pair) of Gfrag per thread.
        const int idx = b * 256 + t;          // 0..2047
        const int ctl = idx >> 2, i = idx & 3;
        const int ct = ctl >> 6, l = ctl & 63;
        const int n  = ct * 16 + (l & 15);
        const int kb = (l >> 4) * 8;
        float v[2];
#pragma unroll
        for (int s = 0; s < 2; ++s) {
            const int k = kb + 2 * i + s;
            const int h = k >> 2, r = k & 3;
            float acc = 0.f;
            if (r < 3) {
#pragma unroll
                for (int dh = 0; dh < 16; ++dh)
                    acc += Wv[r * DM + h * 16 + dh] * Wo[(h * 16 + dh) * DM + n];
            }
            v[s] = acc;
        }
        wsu[WS_GF_W + idx] = pack2bf(v[0], v[1]);
        return;
    }
    // block 8: bp and per-head packs (pre-scaled by CL)
    if (t < 128) {
        const int n = t;
        float bv_ = bo[n];
        for (int d = 0; d < DM; ++d) bv_ += bv[d] * Wo[d * DM + n];
        wsf[WS_BP_W + n] = bv_;
    } else if (t < 128 + NH) {
        const int h = t - 128;
        float* o = &wsf[WS_PACK_W + h * 16];
#pragma unroll
        for (int r = 0; r < 3; ++r)
#pragma unroll
            for (int c = 0; c < 3; ++c) {
                float acc = 0.f;
#pragma unroll
                for (int dh = 0; dh < 16; ++dh)
                    acc += Wq[r * DM + h * 16 + dh] * Wk[c * DM + h * 16 + dh];
                o[r * 3 + c] = acc * CL;
            }
#pragma unroll
        for (int r = 0; r < 3; ++r) {
            float aa = 0.f, cc = 0.f;
#pragma unroll
            for (int dh = 0; dh < 16; ++dh) {
                aa += Wq[r * DM + h * 16 + dh] * bk[h * 16 + dh];
                cc += Wk[r * DM + h * 16 + dh] * bq[h * 16 + dh];
            }
            o[9 + r]  = aa * CL;
            o[12 + r] = cc * CL;
        }
        float dd = 0.f;
#pragma unroll
        for (int dh = 0; dh < 16; ++dh) dd += bq[h * 16 + dh] * bk[h * 16 + dh];
        o[15] = dd * CL;
    }
}

__global__ __launch_bounds__(256, 5) void skel_main_kernel(
    const float* __restrict__ x,
    const unsigned* __restrict__ wsu,
    float* __restrict__ out,
    int npos)
{
    const int t = threadIdx.x;
    const long pos0 = (long)blockIdx.x * P;
    const float* wsf = (const float*)wsu;

    __shared__ __align__(16) float    sx4[P][NJ][4];      // {x,y,z,0} per joint (2 KB)
    __shared__ float                  sc[NH][17];         // per-head packs, padded rows
    __shared__ float                  sadj[NJ][17];       // adjacency * CL, padded rows
    __shared__ __align__(16) float    sbp[128];           // b'
    __shared__ __align__(16) unsigned sxb[4][NJ * 20];    // XB rows, stride 20 u32 (5 KB)
    __shared__ __align__(16) float    sout[4][2][NJ*32];  // ct-pair staging, dbuf (16 KB)

    // ---- stage (one barrier total) -------------------------------------
    sadj[t >> 4][t & 15] = c_adj[t] * CL;
    if (t < 128) {
        const int p = t >> 4, j = t & 15;
        const long pidx = pos0 + p;
        const long base = pidx * 48 + j * 3;
        const bool ok = pidx < npos;
        sx4[p][j][0] = ok ? x[base + 0] : 0.f;
        sx4[p][j][1] = ok ? x[base + 1] : 0.f;
        sx4[p][j][2] = ok ? x[base + 2] : 0.f;
        sx4[p][j][3] = 0.f;
    } else {
        const int i = t - 128;
        sc[i >> 4][i & 15] = wsf[WS_PACK_W + i];
        sbp[i] = wsf[WS_BP_W + i];
    }
    // G fragments straight to registers (coalesced 1KB/instr, L2-resident)
    const int l = t & 63;
    bf16x8 ga[8];
#pragma unroll
    for (int ct = 0; ct < 8; ++ct)
        ga[ct] = *(const bf16x8*)&wsu[WS_GF_W + (ct * 64 + l) * 4];
    __syncthreads();   // the ONLY barrier

    // ---- wave-autonomous processing ------------------------------------
    const int wv = t >> 6;
    const int h  = l >> 3, j0 = l & 7;     // lane owns joints j0 and j0+8 of head h
    const int jB = l & 15, lkB = l >> 4;   // MFMA fragment ids
    const int rS = l >> 3, uS = l & 7;     // store ids: row rS/rS+8, 16B-unit uS

    for (int it = 0; it < 2; ++it) {
        const int p = wv * 2 + it;
        const f32x4 xa = *(const f32x4*)&sx4[p][j0];
        const f32x4 xb = *(const f32x4*)&sx4[p][j0 + 8];

        // y_j = M^T x_j + c' ; u_j = a'.x_j + d'  (pack read from padded LDS)
        const float m0 = sc[h][0],  m1 = sc[h][1],  m2 = sc[h][2];
        const float m3 = sc[h][3],  m4 = sc[h][4],  m5 = sc[h][5];
        const float m6 = sc[h][6],  m7 = sc[h][7],  m8 = sc[h][8];
        const float m9 = sc[h][9],  mA = sc[h][10], mB = sc[h][11];
        const float mC = sc[h][12], mD = sc[h][13], mE = sc[h][14], mF = sc[h][15];

        const float y00 = m0*xa.x + m3*xa.y + m6*xa.z + mC;
        const float y01 = m1*xa.x + m4*xa.y + m7*xa.z + mD;
        const float y02 = m2*xa.x + m5*xa.y + m8*xa.z + mE;
        const float u0  = m9*xa.x + mA*xa.y + mB*xa.z + mF;
        const float y10 = m0*xb.x + m3*xb.y + m6*xb.z + mC;
        const float y11 = m1*xb.x + m4*xb.y + m7*xb.z + mD;
        const float y12 = m2*xb.x + m5*xb.y + m8*xb.z + mE;
        const float u1  = m9*xb.x + mA*xb.y + mB*xb.z + mF;

        float sum0 = 0.f, sum1 = 0.f;
        float a00 = 0.f, a01 = 0.f, a02 = 0.f;
        float a10 = 0.f, a11 = 0.f, a12 = 0.f;
#pragma unroll
        for (int k = 0; k < NJ; ++k) {
            const f32x4 xk = *(const f32x4*)&sx4[p][k];    // broadcast read
            const float ad0 = sadj[j0][k];                 // 8 rows -> 8 banks (pad 17)
            const float ad1 = sadj[j0 + 8][k];
            const float e0 = exp2f(y00*xk.x + y01*xk.y + y02*xk.z + (u0 + ad0));
            const float e1 = exp2f(y10*xk.x + y11*xk.y + y12*xk.z + (u1 + ad1));
            sum0 += e0; sum1 += e1;
            a00 += e0 * xk.x; a01 += e0 * xk.y; a02 += e0 * xk.z;
            a10 += e1 * xk.x; a11 += e1 * xk.y; a12 += e1 * xk.z;
        }
        const float inv0 = __builtin_amdgcn_rcpf(sum0);
        const float inv1 = __builtin_amdgcn_rcpf(sum1);

        // pack XB fragment rows (k = 4h+r, r==3 -> 0); row stride 20 u32
        {
            uint2 w0, w1;
            w0.x = pack2bf(a00 * inv0, a01 * inv0);
            w0.y = pack2bf(a02 * inv0, 0.f);
            w1.x = pack2bf(a10 * inv1, a11 * inv1);
            w1.y = pack2bf(a12 * inv1, 0.f);
            *(uint2*)&sxb[wv][j0 * 20 + 2 * h]       = w0;
            *(uint2*)&sxb[wv][(j0 + 8) * 20 + 2 * h] = w1;
        }
        // intra-wave ds_write -> ds_read (compiler lgkmcnt; no barrier)
        const bf16x8 bvec = *(const bf16x8*)&sxb[wv][jB * 20 + lkB * 4];

        const bool ok = (pos0 + p) < npos;
        float* ob = out + (pos0 + p) * (long)(NJ * DM);

        // ---- ct-pair pipeline: MFMA x2 -> swizzled stage -> store 2KB --
#pragma unroll
        for (int pr = 0; pr < 4; ++pr) {
            float* sb = &sout[wv][pr & 1][0];              // 16 rows x 32 floats

            f32x4 acc0 = *(const f32x4*)&sbp[(2*pr)   * 16 + lkB * 4];
            f32x4 acc1 = *(const f32x4*)&sbp[(2*pr+1) * 16 + lkB * 4];
            acc0 = __builtin_amdgcn_mfma_f32_16x16x32_bf16(ga[2*pr],   bvec, acc0, 0, 0, 0);
            acc1 = __builtin_amdgcn_mfma_f32_16x16x32_bf16(ga[2*pr+1], bvec, acc1, 0, 0, 0);

            // stage: row jB, logical unit (ct_local*4+lkB), phys = u ^ (jB&7)
            *(f32x4*)&sb[jB * 32 + (( lkB      ) ^ (jB & 7)) * 4] = acc0;
            *(f32x4*)&sb[jB * 32 + (( 4 + lkB  ) ^ (jB & 7)) * 4] = acc1;

            if (ok) {
                // rows rS and rS+8, cols pr*32 + uS*4 (full 128B lines)
                const f32x4 v1 = *(const f32x4*)&sb[ rS      * 32 + (uS ^ ( rS      & 7)) * 4];
                const f32x4 v2 = *(const f32x4*)&sb[(rS + 8) * 32 + (uS ^ ((rS + 8) & 7)) * 4];
                *(f32x4*)(ob +  rS      * DM + pr * 32 + uS * 4) = v1;
                *(f32x4*)(ob + (rS + 8) * DM + pr * 32 + uS * 4) = v2;
            }
        }
    }
}

extern "C" void kernel_launch(void* const* d_in, const int* in_sizes, int n_in,
                              void* d_out, int out_size, void* d_ws, size_t ws_size,
                              hipStream_t stream) {
    const float* x  = (const float*)d_in[0];
    const float* Wq = (const float*)d_in[1];
    const float* bq = (const float*)d_in[2];
    const float* Wk = (const float*)d_in[3];
    const float* bk = (const float*)d_in[4];
    const float* Wv = (const float*)d_in[5];
    const float* bv = (const float*)d_in[6];
    const float* Wo = (const float*)d_in[7];
    const float* bo = (const float*)d_in[8];
    float* out    = (float*)d_out;
    unsigned* wsu = (unsigned*)d_ws;

    const int npos = in_sizes[0] / (NJ * 3);   // B*S
    skel_setup_kernel<<<9, 256, 0, stream>>>(Wq, bq, Wk, bk, Wv, bv, Wo, bo, wsu);
    const int grid = (npos + P - 1) / P;
    skel_main_kernel<<<grid, 256, 0, stream>>>(x, wsu, out, npos);
}